// Round 10
// baseline (195.716 us; speedup 1.0000x reference)
//
#include <hip/hip_runtime.h>
#include <cstdint>
#include <cstddef>

// Fused MHA forward: LN -> QKV proj (bf16 MFMA) -> flash attention -> fp32 out.
// R10: qkv_gemm gets the attn-proven pipeline: fragment-order A/B LDS (conflict-free
// sequential ds_reads), double-buffer with counted vmcnt(8) + raw barriers (loads in
// flight across K-steps, no mid-loop drain), XCD-pinned grid (B panels L2-resident).
// attn/ln/wconv/vt byte-identical to R9.
// Workspace layout (ushorts): xn[8192*1024] | Wcat[3072*1024] | Q,K,V,Vt[64*2048*64 each]

typedef __attribute__((ext_vector_type(8))) __bf16 bf16x8;
typedef __attribute__((ext_vector_type(4))) float f32x4;
typedef __attribute__((ext_vector_type(16))) float f32x16;
typedef __attribute__((ext_vector_type(4))) unsigned int u32x4;

#define LOG2E 1.4426950408889634f
#define QSCALE (0.125f * LOG2E)  // 1/sqrt(64) * log2(e), folded into Wq/bq

static __device__ __forceinline__ unsigned short f2bf(float f) {
  union { float f; unsigned int u; } v; v.f = f;
  unsigned int r = v.u + 0x7fffu + ((v.u >> 16) & 1u);
  return (unsigned short)(r >> 16);
}

static __device__ __forceinline__ void gload16(const void* g, void* l) {
  __builtin_amdgcn_global_load_lds(
      (const __attribute__((address_space(1))) unsigned int*)g,
      (__attribute__((address_space(3))) unsigned int*)l, 16, 0, 0);
}

static __device__ __forceinline__ f32x4 mfma16(bf16x8 a, bf16x8 b, f32x4 c) {
  return __builtin_amdgcn_mfma_f32_16x16x32_bf16(a, b, c, 0, 0, 0);
}

static __device__ __forceinline__ f32x16 mfma32(bf16x8 a, bf16x8 b, f32x16 c) {
  return __builtin_amdgcn_mfma_f32_32x32x16_bf16(a, b, c, 0, 0, 0);
}

static __device__ __forceinline__ unsigned int cvtpk(float lo, float hi) {
  unsigned int r;
  asm("v_cvt_pk_bf16_f32 %0, %1, %2" : "=v"(r) : "v"(lo), "v"(hi));
  return r;
}

// v_permlane32_swap_b32: a'[l<32]=a[l], a'[l>=32]=b[l-32]; b'[l<32]=a[l+32], b'[l>=32]=b[l]
static __device__ __forceinline__ void swap32(unsigned int& a, unsigned int& b) {
  asm("v_permlane32_swap_b32 %0, %1" : "+v"(a), "+v"(b));
}

// ---------------- LayerNorm: x fp32 [8192][1024] -> xn bf16 ----------------
__global__ __launch_bounds__(256) void ln_kernel(
    const float* __restrict__ x, const float* __restrict__ gamma,
    const float* __restrict__ beta, unsigned short* __restrict__ xn) {
  const int row = blockIdx.x;
  const int t = threadIdx.x;
  const float4 v = ((const float4*)(x + (size_t)row * 1024))[t];
  float s = v.x + v.y + v.z + v.w;
  float sq = v.x * v.x + v.y * v.y + v.z * v.z + v.w * v.w;
#pragma unroll
  for (int o = 1; o < 64; o <<= 1) { s += __shfl_xor(s, o); sq += __shfl_xor(sq, o); }
  __shared__ float red[2][4];
  const int lane = t & 63, w = t >> 6;
  if (lane == 0) { red[0][w] = s; red[1][w] = sq; }
  __syncthreads();
  s = red[0][0] + red[0][1] + red[0][2] + red[0][3];
  sq = red[1][0] + red[1][1] + red[1][2] + red[1][3];
  const float mean = s * (1.0f / 1024.0f);
  const float var = sq * (1.0f / 1024.0f) - mean * mean;
  const float rs = rsqrtf(var + 1e-5f);
  const float4 g4 = ((const float4*)gamma)[t];
  const float4 b4 = ((const float4*)beta)[t];
  ushort4 o4;
  o4.x = f2bf((v.x - mean) * rs * g4.x + b4.x);
  o4.y = f2bf((v.y - mean) * rs * g4.y + b4.y);
  o4.z = f2bf((v.z - mean) * rs * g4.z + b4.z);
  o4.w = f2bf((v.w - mean) * rs * g4.w + b4.w);
  ((ushort4*)(xn + (size_t)row * 1024))[t] = o4;
}

// ---- Weight convert fp32 -> bf16 concat [3072][1024]; Wq scaled by QSCALE ----
__global__ __launch_bounds__(256) void wconv_kernel(
    const float* __restrict__ Wq, const float* __restrict__ Wk,
    const float* __restrict__ Wv, unsigned short* __restrict__ Wcat) {
  const int idx = blockIdx.x * 256 + threadIdx.x;  // 786432 threads x 4 elems
  const int which = idx >> 18;
  const int off = (idx & 262143) << 2;
  const float* src = which == 0 ? Wq : (which == 1 ? Wk : Wv);
  const float sc = which == 0 ? QSCALE : 1.0f;
  float4 v = *(const float4*)(src + off);
  ushort4 o;
  o.x = f2bf(v.x * sc); o.y = f2bf(v.y * sc);
  o.z = f2bf(v.z * sc); o.w = f2bf(v.w * sc);
  *(ushort4*)(Wcat + ((size_t)which << 20) + off) = o;
}

// -------- QKV GEMM: C[8192,3072] = xn @ Wcat^T, scatter to [B,H,S,64] --------
// R10: fragment-order LDS (slot s = element lane s&63 of fragment s>>6 reads;
// fragment = rowblk*2+ks, element = tile[rowblk*16 + (l&15)][ks*32 + (l>>4)*8]),
// double-buffered with counted vmcnt(8), 2 raw barriers per K-step, XCD-pinned grid.
__global__ __launch_bounds__(256) void qkv_gemm(
    const unsigned short* __restrict__ xn, const unsigned short* __restrict__ Wcat,
    const float* __restrict__ bq, const float* __restrict__ bk,
    const float* __restrict__ bv, unsigned short* __restrict__ Q,
    unsigned short* __restrict__ K, unsigned short* __restrict__ V) {
  __shared__ __align__(16) unsigned short Ash[2][128 * 64];
  __shared__ __align__(16) unsigned short Bsh[2][128 * 64];
  // XCD-pinned decode: grid is 1536 1D; each XCD owns 3 n-panels x 64 m-blocks.
  const int xcd = blockIdx.x & 7, blk = blockIdx.x >> 3;
  const int m0 = (blk & 63) * 128;
  const int n0 = (xcd * 3 + (blk >> 6)) * 128;
  const int t = threadIdx.x;
  const int lane = t & 63, w = t >> 6;
  const int wr = w >> 1, wc = w & 1;
  const int c15 = lane & 15, g = lane >> 4;
  // Fragment-order staging: thread t, iter i covers slot s = i*256+t,
  // frag = i*4+w, lane_s = t&63. Same offsets valid for A and B tiles.
  int soff[4];
#pragma unroll
  for (int i = 0; i < 4; ++i) {
    const int frag = i * 4 + w;
    soff[i] = ((frag >> 1) * 16 + c15) * 1024 + (frag & 1) * 32 + g * 8;
  }
  const unsigned short* Axn = xn + (size_t)m0 * 1024;
  const unsigned short* Bwc = Wcat + (size_t)n0 * 1024;

#define GSTAGE(ktv, bb)                                               \
  {                                                                   \
    _Pragma("unroll") for (int i = 0; i < 4; ++i) {                   \
      gload16(Axn + soff[i] + (ktv) * 64, &Ash[bb][(i * 256 + w * 64) * 8]); \
      gload16(Bwc + soff[i] + (ktv) * 64, &Bsh[bb][(i * 256 + w * 64) * 8]); \
    }                                                                 \
  }

  f32x4 acc[4][4] = {};
  GSTAGE(0, 0);
  GSTAGE(1, 1);
  for (int kt = 0; kt < 16; ++kt) {
    const int cb = kt & 1;
    if (kt == 15) {
      asm volatile("s_waitcnt vmcnt(0)" ::: "memory");
    } else {
      asm volatile("s_waitcnt vmcnt(8)" ::: "memory");  // tile kt landed; kt+1 in flight
    }
    __builtin_amdgcn_s_barrier();  // all waves' tile-kt loads landed
    __builtin_amdgcn_s_setprio(1);
#pragma unroll
    for (int ks = 0; ks < 2; ++ks) {
      bf16x8 af[4], bfv[4];
#pragma unroll
      for (int mi = 0; mi < 4; ++mi)
        af[mi] = *(const bf16x8*)&Ash[cb][(((wr * 4 + mi) * 2 + ks) * 64 + lane) * 8];
#pragma unroll
      for (int ni = 0; ni < 4; ++ni)
        bfv[ni] = *(const bf16x8*)&Bsh[cb][(((wc * 4 + ni) * 2 + ks) * 64 + lane) * 8];
#pragma unroll
      for (int mi = 0; mi < 4; ++mi)
#pragma unroll
        for (int ni = 0; ni < 4; ++ni)
          acc[mi][ni] = mfma16(af[mi], bfv[ni], acc[mi][ni]);
    }
    __builtin_amdgcn_s_setprio(0);
    asm volatile("s_waitcnt lgkmcnt(0)" ::: "memory");  // (no-op: reads consumed)
    __builtin_amdgcn_s_barrier();  // all waves done reading buf[cb]
    if (kt + 2 < 16) GSTAGE(kt + 2, cb);
  }
#undef GSTAGE
  const int nsel = n0 >> 10;
  const float* bias = nsel == 0 ? bq : (nsel == 1 ? bk : bv);
  unsigned short* dst = nsel == 0 ? Q : (nsel == 1 ? K : V);
  const float bscale = nsel == 0 ? QSCALE : 1.0f;
#pragma unroll
  for (int ni = 0; ni < 4; ++ni) {
    const int ncol = (n0 & 1023) + wc * 64 + ni * 16 + c15;
    const float bb = bias[ncol] * bscale;
    const int h = ncol >> 6, dk = ncol & 63;
#pragma unroll
    for (int mi = 0; mi < 4; ++mi) {
#pragma unroll
      for (int r = 0; r < 4; ++r) {
        const int m = m0 + wr * 64 + mi * 16 + g * 4 + r;
        const int b = m >> 11, sI = m & 2047;
        dst[((size_t)((b * 16 + h) * 2048 + sI)) * 64 + dk] = f2bf(acc[mi][ni][r] + bb);
      }
    }
  }
}

// ------------- V [bh][s][64] -> Vt [bh][64][s] (64x64 LDS tiles) -------------
__global__ __launch_bounds__(256) void vt_kernel(
    const unsigned short* __restrict__ V, unsigned short* __restrict__ Vt) {
  __shared__ unsigned short tile[64][65];
  const int st = blockIdx.x, bh = blockIdx.y;
  const int t = threadIdx.x;
  const unsigned short* Vb = V + ((size_t)bh * 2048 + st * 64) * 64;
#pragma unroll
  for (int i = 0; i < 2; ++i) {
    const int li = i * 256 + t;
    const int s = li >> 3, c = li & 7;
    ushort4 a = *(const ushort4*)(Vb + s * 64 + c * 8);
    ushort4 b = *(const ushort4*)(Vb + s * 64 + c * 8 + 4);
    tile[s][c * 8 + 0] = a.x; tile[s][c * 8 + 1] = a.y;
    tile[s][c * 8 + 2] = a.z; tile[s][c * 8 + 3] = a.w;
    tile[s][c * 8 + 4] = b.x; tile[s][c * 8 + 5] = b.y;
    tile[s][c * 8 + 6] = b.z; tile[s][c * 8 + 7] = b.w;
  }
  __syncthreads();
  unsigned short* dst = Vt + (size_t)bh * 64 * 2048 + st * 64;
#pragma unroll
  for (int i = 0; i < 2; ++i) {
    const int li = i * 256 + t;
    const int d = li >> 3, c = li & 7;
    ushort4 o1, o2;
    o1.x = tile[c * 8 + 0][d]; o1.y = tile[c * 8 + 1][d];
    o1.z = tile[c * 8 + 2][d]; o1.w = tile[c * 8 + 3][d];
    o2.x = tile[c * 8 + 4][d]; o2.y = tile[c * 8 + 5][d];
    o2.z = tile[c * 8 + 6][d]; o2.w = tile[c * 8 + 7][d];
    *(ushort4*)(dst + (size_t)d * 2048 + c * 8) = o1;
    *(ushort4*)(dst + (size_t)d * 2048 + c * 8 + 4) = o2;
  }
}

// ---- flash attention: block = (qt,bh), 256 q-rows, 8 waves x 32 q, 32 KV tiles ----
// Grid 512 blocks 1D; bh%8 == blockIdx.x%8 pins each bh's 8 qt-blocks to one XCD.
// K/V LDS in FRAGMENT ORDER -> ds_read addresses are base + lane*16B (conflict-free).
// 3-buffer staging, counted vmcnt(2), 1 raw barrier/tile.
__global__ __launch_bounds__(512) void attn_kernel(
    const unsigned short* __restrict__ Q, const unsigned short* __restrict__ K,
    const unsigned short* __restrict__ Vt, float* __restrict__ out) {
  __shared__ __align__(16) unsigned short Ksh[3][64 * 64];
  __shared__ __align__(16) unsigned short Vsh[3][64 * 64];
  const int id = blockIdx.x;
  const int k7 = id >> 3;
  const int qt = k7 & 7, bh = (id & 7) + 8 * (k7 >> 3);
  const int t = threadIdx.x, lane = t & 63, w = t >> 6;
  const int l31 = lane & 31, hi = lane >> 5;
  const int b = bh >> 4, h = bh & 15;
  const unsigned short* Qb = Q + (size_t)bh * 2048 * 64;
  const unsigned short* Kb = K + (size_t)bh * 2048 * 64;
  const unsigned short* Vb = Vt + (size_t)bh * 64 * 2048;
  const int q0w = qt * 256 + w * 32;
  // Q as B-operand frags (reg-resident): lane holds Q[q0w+l31][8*hi+j+16*ds]
  bf16x8 qf[4];
#pragma unroll
  for (int ds = 0; ds < 4; ++ds)
    qf[ds] = *(const bf16x8*)(Qb + (size_t)(q0w + l31) * 64 + ds * 16 + hi * 8);
  bf16x8 ones;
#pragma unroll
  for (int j = 0; j < 8; ++j) ones[j] = (__bf16)1.0f;
  f32x16 oacc[2] = {};
  f32x16 lacc = {};

  // Fragment-order staging sources (per-thread constants)
  const int sl31 = t & 31, shi = (t >> 5) & 1;
  const int skb = t >> 8, sds = (t >> 6) & 3;
  const int sks = t >> 7, sdb = (t >> 6) & 1;
  const unsigned short* Ksrc = Kb + (size_t)(skb * 32 + sl31) * 64 + (sds * 2 + shi) * 8;
  const unsigned short* Vsrc = Vb + (size_t)(sdb * 32 + sl31) * 2048 + (sks * 2 + shi) * 8;

#define STAGE(kvt, bb)                                       \
  {                                                          \
    gload16(Ksrc + (size_t)(kvt) * 4096, &Ksh[bb][w * 512]); \
    gload16(Vsrc + (size_t)(kvt) * 64, &Vsh[bb][w * 512]);   \
  }

  STAGE(0, 0);
  STAGE(1, 1);
  int bufc = 0;  // buffer holding tile kv
  for (int kv = 0; kv < 32; ++kv) {
    if (kv == 31) {
      asm volatile("s_waitcnt vmcnt(0)" ::: "memory");
    } else {
      asm volatile("s_waitcnt vmcnt(2)" ::: "memory");  // own tile-kv loads landed
    }
    __builtin_amdgcn_s_barrier();  // all waves' tile-kv loads landed
    bf16x8 pa[4];
#pragma unroll
    for (int kb = 0; kb < 2; ++kb) {
      f32x16 s = {};
      __builtin_amdgcn_s_setprio(1);
#pragma unroll
      for (int ds = 0; ds < 4; ++ds) {
        bf16x8 ak = *(const bf16x8*)&Ksh[bufc][((kb * 4 + ds) * 64 + lane) * 8];
        s = mfma32(ak, qf[ds], s);
      }
      __builtin_amdgcn_s_setprio(0);
      // P = exp2(S) (S in log2-domain), pack to bf16 pairs, cross-lane assemble.
      unsigned int wd[8];
#pragma unroll
      for (int i = 0; i < 8; ++i)
        wd[i] = cvtpk(__builtin_amdgcn_exp2f(s[2 * i]),
                      __builtin_amdgcn_exp2f(s[2 * i + 1]));
      swap32(wd[0], wd[2]); swap32(wd[1], wd[3]);
      swap32(wd[4], wd[6]); swap32(wd[5], wd[7]);
      const u32x4 fa = {wd[0], wd[1], wd[2], wd[3]};
      const u32x4 fb = {wd[4], wd[5], wd[6], wd[7]};
      pa[kb * 2]     = __builtin_bit_cast(bf16x8, fa);
      pa[kb * 2 + 1] = __builtin_bit_cast(bf16x8, fb);
    }
    // PV + row-sum: A = P (regs), B = Vt / ones
    __builtin_amdgcn_s_setprio(1);
#pragma unroll
    for (int ks = 0; ks < 4; ++ks) {
      lacc = mfma32(pa[ks], ones, lacc);
#pragma unroll
      for (int db = 0; db < 2; ++db) {
        bf16x8 bv8 = *(const bf16x8*)&Vsh[bufc][((ks * 2 + db) * 64 + lane) * 8];
        oacc[db] = mfma32(pa[ks], bv8, oacc[db]);
      }
    }
    __builtin_amdgcn_s_setprio(0);
    // Prefetch tile kv+2 into the buffer being retired (disjoint from kv, kv+1)
    if (kv + 2 < 32) {
      int nb = bufc + 2; if (nb >= 3) nb -= 3;
      STAGE(kv + 2, nb);
    }
    bufc = (bufc + 1 == 3) ? 0 : bufc + 1;
  }
#undef STAGE
  // Epilogue: D layout col=l31 (=d within 32-block), row q = (r&3)+8*(r>>2)+4*hi
#pragma unroll
  for (int r = 0; r < 16; ++r) {
    const float inv = 1.0f / lacc[r];
    const int q = q0w + (r & 3) + 8 * (r >> 2) + 4 * hi;
    const size_t base = ((size_t)(b * 2048 + q)) * 1024 + h * 64;
    out[base + l31] = oacc[0][r] * inv;
    out[base + 32 + l31] = oacc[1][r] * inv;
  }
}

extern "C" void kernel_launch(void* const* d_in, const int* in_sizes, int n_in,
                              void* d_out, int out_size, void* d_ws, size_t ws_size,
                              hipStream_t stream) {
  const float* x   = (const float*)d_in[0];
  const float* Wq  = (const float*)d_in[1];
  const float* bq  = (const float*)d_in[2];
  const float* Wk  = (const float*)d_in[3];
  const float* bk  = (const float*)d_in[4];
  const float* Wv  = (const float*)d_in[5];
  const float* bv  = (const float*)d_in[6];
  const float* gam = (const float*)d_in[7];
  const float* bet = (const float*)d_in[8];

  unsigned short* ws   = (unsigned short*)d_ws;
  unsigned short* xn   = ws;                    // 8192*1024
  unsigned short* Wcat = xn + 8192 * 1024;      // 3072*1024
  unsigned short* Qb   = Wcat + 3072 * 1024;    // 64*2048*64
  unsigned short* Kb   = Qb + 64 * 2048 * 64;
  unsigned short* Vb   = Kb + 64 * 2048 * 64;
  unsigned short* Vtb  = Vb + 64 * 2048 * 64;
  float* outp = (float*)d_out;  // fp32 output (reference returns float32)

  hipLaunchKernelGGL(ln_kernel, dim3(8192), dim3(256), 0, stream, x, gam, bet, xn);
  hipLaunchKernelGGL(wconv_kernel, dim3(3072), dim3(256), 0, stream, Wq, Wk, Wv, Wcat);
  hipLaunchKernelGGL(qkv_gemm, dim3(1536), dim3(256), 0, stream,
                     xn, Wcat, bq, bk, bv, Qb, Kb, Vb);
  hipLaunchKernelGGL(vt_kernel, dim3(32, 64), dim3(256), 0, stream, Vb, Vtb);
  hipLaunchKernelGGL(attn_kernel, dim3(512), dim3(512), 0, stream, Qb, Kb, Vtb, outp);
}

// Round 11
// 192.971 us; speedup vs baseline: 1.0142x; 1.0142x over previous
//
#include <hip/hip_runtime.h>
#include <cstdint>
#include <cstddef>

// Fused MHA forward: LN -> QKV proj (bf16 MFMA) -> flash attention -> fp32 out.
// R11: qkv_gemm = R10's fragment-order LDS + counted-vmcnt(8) double-buffer pipeline
// but with R9's 2D grid (64,24) dispatch (XCD pinning reverted: it streamed the full
// 16MB A per XCD per n-panel -> 200MB L2-miss traffic; 2D round-robin spreads the
// A-sweep across all 8 L2s -> 49MB). attn/ln/wconv/vt byte-identical to R9/R10.
// Workspace layout (ushorts): xn[8192*1024] | Wcat[3072*1024] | Q,K,V,Vt[64*2048*64 each]

typedef __attribute__((ext_vector_type(8))) __bf16 bf16x8;
typedef __attribute__((ext_vector_type(4))) float f32x4;
typedef __attribute__((ext_vector_type(16))) float f32x16;
typedef __attribute__((ext_vector_type(4))) unsigned int u32x4;

#define LOG2E 1.4426950408889634f
#define QSCALE (0.125f * LOG2E)  // 1/sqrt(64) * log2(e), folded into Wq/bq

static __device__ __forceinline__ unsigned short f2bf(float f) {
  union { float f; unsigned int u; } v; v.f = f;
  unsigned int r = v.u + 0x7fffu + ((v.u >> 16) & 1u);
  return (unsigned short)(r >> 16);
}

static __device__ __forceinline__ void gload16(const void* g, void* l) {
  __builtin_amdgcn_global_load_lds(
      (const __attribute__((address_space(1))) unsigned int*)g,
      (__attribute__((address_space(3))) unsigned int*)l, 16, 0, 0);
}

static __device__ __forceinline__ f32x4 mfma16(bf16x8 a, bf16x8 b, f32x4 c) {
  return __builtin_amdgcn_mfma_f32_16x16x32_bf16(a, b, c, 0, 0, 0);
}

static __device__ __forceinline__ f32x16 mfma32(bf16x8 a, bf16x8 b, f32x16 c) {
  return __builtin_amdgcn_mfma_f32_32x32x16_bf16(a, b, c, 0, 0, 0);
}

static __device__ __forceinline__ unsigned int cvtpk(float lo, float hi) {
  unsigned int r;
  asm("v_cvt_pk_bf16_f32 %0, %1, %2" : "=v"(r) : "v"(lo), "v"(hi));
  return r;
}

// v_permlane32_swap_b32: a'[l<32]=a[l], a'[l>=32]=b[l-32]; b'[l<32]=a[l+32], b'[l>=32]=b[l]
static __device__ __forceinline__ void swap32(unsigned int& a, unsigned int& b) {
  asm("v_permlane32_swap_b32 %0, %1" : "+v"(a), "+v"(b));
}

// ---------------- LayerNorm: x fp32 [8192][1024] -> xn bf16 ----------------
__global__ __launch_bounds__(256) void ln_kernel(
    const float* __restrict__ x, const float* __restrict__ gamma,
    const float* __restrict__ beta, unsigned short* __restrict__ xn) {
  const int row = blockIdx.x;
  const int t = threadIdx.x;
  const float4 v = ((const float4*)(x + (size_t)row * 1024))[t];
  float s = v.x + v.y + v.z + v.w;
  float sq = v.x * v.x + v.y * v.y + v.z * v.z + v.w * v.w;
#pragma unroll
  for (int o = 1; o < 64; o <<= 1) { s += __shfl_xor(s, o); sq += __shfl_xor(sq, o); }
  __shared__ float red[2][4];
  const int lane = t & 63, w = t >> 6;
  if (lane == 0) { red[0][w] = s; red[1][w] = sq; }
  __syncthreads();
  s = red[0][0] + red[0][1] + red[0][2] + red[0][3];
  sq = red[1][0] + red[1][1] + red[1][2] + red[1][3];
  const float mean = s * (1.0f / 1024.0f);
  const float var = sq * (1.0f / 1024.0f) - mean * mean;
  const float rs = rsqrtf(var + 1e-5f);
  const float4 g4 = ((const float4*)gamma)[t];
  const float4 b4 = ((const float4*)beta)[t];
  ushort4 o4;
  o4.x = f2bf((v.x - mean) * rs * g4.x + b4.x);
  o4.y = f2bf((v.y - mean) * rs * g4.y + b4.y);
  o4.z = f2bf((v.z - mean) * rs * g4.z + b4.z);
  o4.w = f2bf((v.w - mean) * rs * g4.w + b4.w);
  ((ushort4*)(xn + (size_t)row * 1024))[t] = o4;
}

// ---- Weight convert fp32 -> bf16 concat [3072][1024]; Wq scaled by QSCALE ----
__global__ __launch_bounds__(256) void wconv_kernel(
    const float* __restrict__ Wq, const float* __restrict__ Wk,
    const float* __restrict__ Wv, unsigned short* __restrict__ Wcat) {
  const int idx = blockIdx.x * 256 + threadIdx.x;  // 786432 threads x 4 elems
  const int which = idx >> 18;
  const int off = (idx & 262143) << 2;
  const float* src = which == 0 ? Wq : (which == 1 ? Wk : Wv);
  const float sc = which == 0 ? QSCALE : 1.0f;
  float4 v = *(const float4*)(src + off);
  ushort4 o;
  o.x = f2bf(v.x * sc); o.y = f2bf(v.y * sc);
  o.z = f2bf(v.z * sc); o.w = f2bf(v.w * sc);
  *(ushort4*)(Wcat + ((size_t)which << 20) + off) = o;
}

// -------- QKV GEMM: C[8192,3072] = xn @ Wcat^T, scatter to [B,H,S,64] --------
// Fragment-order LDS (conflict-free), double-buffer + counted vmcnt(8),
// 2 raw barriers per K-step, 2D grid (64,24) for cross-XCD A-sweep spreading.
__global__ __launch_bounds__(256) void qkv_gemm(
    const unsigned short* __restrict__ xn, const unsigned short* __restrict__ Wcat,
    const float* __restrict__ bq, const float* __restrict__ bk,
    const float* __restrict__ bv, unsigned short* __restrict__ Q,
    unsigned short* __restrict__ K, unsigned short* __restrict__ V) {
  __shared__ __align__(16) unsigned short Ash[2][128 * 64];
  __shared__ __align__(16) unsigned short Bsh[2][128 * 64];
  const int m0 = blockIdx.x * 128;
  const int n0 = blockIdx.y * 128;
  const int t = threadIdx.x;
  const int lane = t & 63, w = t >> 6;
  const int wr = w >> 1, wc = w & 1;
  const int c15 = lane & 15, g = lane >> 4;
  // Fragment-order staging: thread t, iter i covers slot s = i*256+t,
  // frag = i*4+w, lane_s = t&63. Same offsets valid for A and B tiles.
  int soff[4];
#pragma unroll
  for (int i = 0; i < 4; ++i) {
    const int frag = i * 4 + w;
    soff[i] = ((frag >> 1) * 16 + c15) * 1024 + (frag & 1) * 32 + g * 8;
  }
  const unsigned short* Axn = xn + (size_t)m0 * 1024;
  const unsigned short* Bwc = Wcat + (size_t)n0 * 1024;

#define GSTAGE(ktv, bb)                                               \
  {                                                                   \
    _Pragma("unroll") for (int i = 0; i < 4; ++i) {                   \
      gload16(Axn + soff[i] + (ktv) * 64, &Ash[bb][(i * 256 + w * 64) * 8]); \
      gload16(Bwc + soff[i] + (ktv) * 64, &Bsh[bb][(i * 256 + w * 64) * 8]); \
    }                                                                 \
  }

  f32x4 acc[4][4] = {};
  GSTAGE(0, 0);
  GSTAGE(1, 1);
  for (int kt = 0; kt < 16; ++kt) {
    const int cb = kt & 1;
    if (kt == 15) {
      asm volatile("s_waitcnt vmcnt(0)" ::: "memory");
    } else {
      asm volatile("s_waitcnt vmcnt(8)" ::: "memory");  // tile kt landed; kt+1 in flight
    }
    __builtin_amdgcn_s_barrier();  // all waves' tile-kt loads landed
    __builtin_amdgcn_s_setprio(1);
#pragma unroll
    for (int ks = 0; ks < 2; ++ks) {
      bf16x8 af[4], bfv[4];
#pragma unroll
      for (int mi = 0; mi < 4; ++mi)
        af[mi] = *(const bf16x8*)&Ash[cb][(((wr * 4 + mi) * 2 + ks) * 64 + lane) * 8];
#pragma unroll
      for (int ni = 0; ni < 4; ++ni)
        bfv[ni] = *(const bf16x8*)&Bsh[cb][(((wc * 4 + ni) * 2 + ks) * 64 + lane) * 8];
#pragma unroll
      for (int mi = 0; mi < 4; ++mi)
#pragma unroll
        for (int ni = 0; ni < 4; ++ni)
          acc[mi][ni] = mfma16(af[mi], bfv[ni], acc[mi][ni]);
    }
    __builtin_amdgcn_s_setprio(0);
    asm volatile("s_waitcnt lgkmcnt(0)" ::: "memory");
    __builtin_amdgcn_s_barrier();  // all waves done reading buf[cb]
    if (kt + 2 < 16) GSTAGE(kt + 2, cb);
  }
#undef GSTAGE
  const int nsel = n0 >> 10;
  const float* bias = nsel == 0 ? bq : (nsel == 1 ? bk : bv);
  unsigned short* dst = nsel == 0 ? Q : (nsel == 1 ? K : V);
  const float bscale = nsel == 0 ? QSCALE : 1.0f;
#pragma unroll
  for (int ni = 0; ni < 4; ++ni) {
    const int ncol = (n0 & 1023) + wc * 64 + ni * 16 + c15;
    const float bb = bias[ncol] * bscale;
    const int h = ncol >> 6, dk = ncol & 63;
#pragma unroll
    for (int mi = 0; mi < 4; ++mi) {
#pragma unroll
      for (int r = 0; r < 4; ++r) {
        const int m = m0 + wr * 64 + mi * 16 + g * 4 + r;
        const int b = m >> 11, sI = m & 2047;
        dst[((size_t)((b * 16 + h) * 2048 + sI)) * 64 + dk] = f2bf(acc[mi][ni][r] + bb);
      }
    }
  }
}

// ------------- V [bh][s][64] -> Vt [bh][64][s] (64x64 LDS tiles) -------------
__global__ __launch_bounds__(256) void vt_kernel(
    const unsigned short* __restrict__ V, unsigned short* __restrict__ Vt) {
  __shared__ unsigned short tile[64][65];
  const int st = blockIdx.x, bh = blockIdx.y;
  const int t = threadIdx.x;
  const unsigned short* Vb = V + ((size_t)bh * 2048 + st * 64) * 64;
#pragma unroll
  for (int i = 0; i < 2; ++i) {
    const int li = i * 256 + t;
    const int s = li >> 3, c = li & 7;
    ushort4 a = *(const ushort4*)(Vb + s * 64 + c * 8);
    ushort4 b = *(const ushort4*)(Vb + s * 64 + c * 8 + 4);
    tile[s][c * 8 + 0] = a.x; tile[s][c * 8 + 1] = a.y;
    tile[s][c * 8 + 2] = a.z; tile[s][c * 8 + 3] = a.w;
    tile[s][c * 8 + 4] = b.x; tile[s][c * 8 + 5] = b.y;
    tile[s][c * 8 + 6] = b.z; tile[s][c * 8 + 7] = b.w;
  }
  __syncthreads();
  unsigned short* dst = Vt + (size_t)bh * 64 * 2048 + st * 64;
#pragma unroll
  for (int i = 0; i < 2; ++i) {
    const int li = i * 256 + t;
    const int d = li >> 3, c = li & 7;
    ushort4 o1, o2;
    o1.x = tile[c * 8 + 0][d]; o1.y = tile[c * 8 + 1][d];
    o1.z = tile[c * 8 + 2][d]; o1.w = tile[c * 8 + 3][d];
    o2.x = tile[c * 8 + 4][d]; o2.y = tile[c * 8 + 5][d];
    o2.z = tile[c * 8 + 6][d]; o2.w = tile[c * 8 + 7][d];
    *(ushort4*)(dst + (size_t)d * 2048 + c * 8) = o1;
    *(ushort4*)(dst + (size_t)d * 2048 + c * 8 + 4) = o2;
  }
}

// ---- flash attention: block = (qt,bh), 256 q-rows, 8 waves x 32 q, 32 KV tiles ----
// Grid 512 blocks 1D; bh%8 == blockIdx.x%8 pins each bh's 8 qt-blocks to one XCD.
// K/V LDS in FRAGMENT ORDER -> ds_read addresses are base + lane*16B (conflict-free).
// 3-buffer staging, counted vmcnt(2), 1 raw barrier/tile.
__global__ __launch_bounds__(512) void attn_kernel(
    const unsigned short* __restrict__ Q, const unsigned short* __restrict__ K,
    const unsigned short* __restrict__ Vt, float* __restrict__ out) {
  __shared__ __align__(16) unsigned short Ksh[3][64 * 64];
  __shared__ __align__(16) unsigned short Vsh[3][64 * 64];
  const int id = blockIdx.x;
  const int k7 = id >> 3;
  const int qt = k7 & 7, bh = (id & 7) + 8 * (k7 >> 3);
  const int t = threadIdx.x, lane = t & 63, w = t >> 6;
  const int l31 = lane & 31, hi = lane >> 5;
  const int b = bh >> 4, h = bh & 15;
  const unsigned short* Qb = Q + (size_t)bh * 2048 * 64;
  const unsigned short* Kb = K + (size_t)bh * 2048 * 64;
  const unsigned short* Vb = Vt + (size_t)bh * 64 * 2048;
  const int q0w = qt * 256 + w * 32;
  // Q as B-operand frags (reg-resident): lane holds Q[q0w+l31][8*hi+j+16*ds]
  bf16x8 qf[4];
#pragma unroll
  for (int ds = 0; ds < 4; ++ds)
    qf[ds] = *(const bf16x8*)(Qb + (size_t)(q0w + l31) * 64 + ds * 16 + hi * 8);
  bf16x8 ones;
#pragma unroll
  for (int j = 0; j < 8; ++j) ones[j] = (__bf16)1.0f;
  f32x16 oacc[2] = {};
  f32x16 lacc = {};

  // Fragment-order staging sources (per-thread constants)
  const int sl31 = t & 31, shi = (t >> 5) & 1;
  const int skb = t >> 8, sds = (t >> 6) & 3;
  const int sks = t >> 7, sdb = (t >> 6) & 1;
  const unsigned short* Ksrc = Kb + (size_t)(skb * 32 + sl31) * 64 + (sds * 2 + shi) * 8;
  const unsigned short* Vsrc = Vb + (size_t)(sdb * 32 + sl31) * 2048 + (sks * 2 + shi) * 8;

#define STAGE(kvt, bb)                                       \
  {                                                          \
    gload16(Ksrc + (size_t)(kvt) * 4096, &Ksh[bb][w * 512]); \
    gload16(Vsrc + (size_t)(kvt) * 64, &Vsh[bb][w * 512]);   \
  }

  STAGE(0, 0);
  STAGE(1, 1);
  int bufc = 0;  // buffer holding tile kv
  for (int kv = 0; kv < 32; ++kv) {
    if (kv == 31) {
      asm volatile("s_waitcnt vmcnt(0)" ::: "memory");
    } else {
      asm volatile("s_waitcnt vmcnt(2)" ::: "memory");  // own tile-kv loads landed
    }
    __builtin_amdgcn_s_barrier();  // all waves' tile-kv loads landed
    bf16x8 pa[4];
#pragma unroll
    for (int kb = 0; kb < 2; ++kb) {
      f32x16 s = {};
      __builtin_amdgcn_s_setprio(1);
#pragma unroll
      for (int ds = 0; ds < 4; ++ds) {
        bf16x8 ak = *(const bf16x8*)&Ksh[bufc][((kb * 4 + ds) * 64 + lane) * 8];
        s = mfma32(ak, qf[ds], s);
      }
      __builtin_amdgcn_s_setprio(0);
      // P = exp2(S) (S in log2-domain), pack to bf16 pairs, cross-lane assemble.
      unsigned int wd[8];
#pragma unroll
      for (int i = 0; i < 8; ++i)
        wd[i] = cvtpk(__builtin_amdgcn_exp2f(s[2 * i]),
                      __builtin_amdgcn_exp2f(s[2 * i + 1]));
      swap32(wd[0], wd[2]); swap32(wd[1], wd[3]);
      swap32(wd[4], wd[6]); swap32(wd[5], wd[7]);
      const u32x4 fa = {wd[0], wd[1], wd[2], wd[3]};
      const u32x4 fb = {wd[4], wd[5], wd[6], wd[7]};
      pa[kb * 2]     = __builtin_bit_cast(bf16x8, fa);
      pa[kb * 2 + 1] = __builtin_bit_cast(bf16x8, fb);
    }
    // PV + row-sum: A = P (regs), B = Vt / ones
    __builtin_amdgcn_s_setprio(1);
#pragma unroll
    for (int ks = 0; ks < 4; ++ks) {
      lacc = mfma32(pa[ks], ones, lacc);
#pragma unroll
      for (int db = 0; db < 2; ++db) {
        bf16x8 bv8 = *(const bf16x8*)&Vsh[bufc][((ks * 2 + db) * 64 + lane) * 8];
        oacc[db] = mfma32(pa[ks], bv8, oacc[db]);
      }
    }
    __builtin_amdgcn_s_setprio(0);
    // Prefetch tile kv+2 into the buffer being retired (disjoint from kv, kv+1)
    if (kv + 2 < 32) {
      int nb = bufc + 2; if (nb >= 3) nb -= 3;
      STAGE(kv + 2, nb);
    }
    bufc = (bufc + 1 == 3) ? 0 : bufc + 1;
  }
#undef STAGE
  // Epilogue: D layout col=l31 (=d within 32-block), row q = (r&3)+8*(r>>2)+4*hi
#pragma unroll
  for (int r = 0; r < 16; ++r) {
    const float inv = 1.0f / lacc[r];
    const int q = q0w + (r & 3) + 8 * (r >> 2) + 4 * hi;
    const size_t base = ((size_t)(b * 2048 + q)) * 1024 + h * 64;
    out[base + l31] = oacc[0][r] * inv;
    out[base + 32 + l31] = oacc[1][r] * inv;
  }
}

extern "C" void kernel_launch(void* const* d_in, const int* in_sizes, int n_in,
                              void* d_out, int out_size, void* d_ws, size_t ws_size,
                              hipStream_t stream) {
  const float* x   = (const float*)d_in[0];
  const float* Wq  = (const float*)d_in[1];
  const float* bq  = (const float*)d_in[2];
  const float* Wk  = (const float*)d_in[3];
  const float* bk  = (const float*)d_in[4];
  const float* Wv  = (const float*)d_in[5];
  const float* bv  = (const float*)d_in[6];
  const float* gam = (const float*)d_in[7];
  const float* bet = (const float*)d_in[8];

  unsigned short* ws   = (unsigned short*)d_ws;
  unsigned short* xn   = ws;                    // 8192*1024
  unsigned short* Wcat = xn + 8192 * 1024;      // 3072*1024
  unsigned short* Qb   = Wcat + 3072 * 1024;    // 64*2048*64
  unsigned short* Kb   = Qb + 64 * 2048 * 64;
  unsigned short* Vb   = Kb + 64 * 2048 * 64;
  unsigned short* Vtb  = Vb + 64 * 2048 * 64;
  float* outp = (float*)d_out;  // fp32 output (reference returns float32)

  hipLaunchKernelGGL(ln_kernel, dim3(8192), dim3(256), 0, stream, x, gam, bet, xn);
  hipLaunchKernelGGL(wconv_kernel, dim3(3072), dim3(256), 0, stream, Wq, Wk, Wv, Wcat);
  hipLaunchKernelGGL(qkv_gemm, dim3(64, 24), dim3(256), 0, stream,
                     xn, Wcat, bq, bk, bv, Qb, Kb, Vb);
  hipLaunchKernelGGL(vt_kernel, dim3(32, 64), dim3(256), 0, stream, Vb, Vtb);
  hipLaunchKernelGGL(attn_kernel, dim3(512), dim3(512), 0, stream, Qb, Kb, Vtb, outp);
}

// Round 12
// 170.481 us; speedup vs baseline: 1.1480x; 1.1319x over previous
//
#include <hip/hip_runtime.h>
#include <cstdint>
#include <cstddef>

// Fused MHA forward: LN -> QKV proj (bf16 MFMA) -> flash attention -> fp32 out.
// R12: qkv_gemm rebuilt on the attn-proven skeleton: 256x128 tile, 8 waves
// (4Mx2N, 64x64/wave), mfma_f32_32x32x16 (2x FLOP per ds_read vs 16x16), BK=32,
// 3-buffer fragment-order LDS (72KB, 2 blocks/CU), counted vmcnt(3) + 1 raw
// barrier per K-step, 2D (32,24) grid. attn/ln/wconv/vt byte-identical to R11.
// Workspace layout (ushorts): xn[8192*1024] | Wcat[3072*1024] | Q,K,V,Vt[64*2048*64 each]

typedef __attribute__((ext_vector_type(8))) __bf16 bf16x8;
typedef __attribute__((ext_vector_type(4))) float f32x4;
typedef __attribute__((ext_vector_type(16))) float f32x16;
typedef __attribute__((ext_vector_type(4))) unsigned int u32x4;

#define LOG2E 1.4426950408889634f
#define QSCALE (0.125f * LOG2E)  // 1/sqrt(64) * log2(e), folded into Wq/bq

static __device__ __forceinline__ unsigned short f2bf(float f) {
  union { float f; unsigned int u; } v; v.f = f;
  unsigned int r = v.u + 0x7fffu + ((v.u >> 16) & 1u);
  return (unsigned short)(r >> 16);
}

static __device__ __forceinline__ void gload16(const void* g, void* l) {
  __builtin_amdgcn_global_load_lds(
      (const __attribute__((address_space(1))) unsigned int*)g,
      (__attribute__((address_space(3))) unsigned int*)l, 16, 0, 0);
}

static __device__ __forceinline__ f32x16 mfma32(bf16x8 a, bf16x8 b, f32x16 c) {
  return __builtin_amdgcn_mfma_f32_32x32x16_bf16(a, b, c, 0, 0, 0);
}

static __device__ __forceinline__ unsigned int cvtpk(float lo, float hi) {
  unsigned int r;
  asm("v_cvt_pk_bf16_f32 %0, %1, %2" : "=v"(r) : "v"(lo), "v"(hi));
  return r;
}

// v_permlane32_swap_b32: a'[l<32]=a[l], a'[l>=32]=b[l-32]; b'[l<32]=a[l+32], b'[l>=32]=b[l]
static __device__ __forceinline__ void swap32(unsigned int& a, unsigned int& b) {
  asm("v_permlane32_swap_b32 %0, %1" : "+v"(a), "+v"(b));
}

// ---------------- LayerNorm: x fp32 [8192][1024] -> xn bf16 ----------------
__global__ __launch_bounds__(256) void ln_kernel(
    const float* __restrict__ x, const float* __restrict__ gamma,
    const float* __restrict__ beta, unsigned short* __restrict__ xn) {
  const int row = blockIdx.x;
  const int t = threadIdx.x;
  const float4 v = ((const float4*)(x + (size_t)row * 1024))[t];
  float s = v.x + v.y + v.z + v.w;
  float sq = v.x * v.x + v.y * v.y + v.z * v.z + v.w * v.w;
#pragma unroll
  for (int o = 1; o < 64; o <<= 1) { s += __shfl_xor(s, o); sq += __shfl_xor(sq, o); }
  __shared__ float red[2][4];
  const int lane = t & 63, w = t >> 6;
  if (lane == 0) { red[0][w] = s; red[1][w] = sq; }
  __syncthreads();
  s = red[0][0] + red[0][1] + red[0][2] + red[0][3];
  sq = red[1][0] + red[1][1] + red[1][2] + red[1][3];
  const float mean = s * (1.0f / 1024.0f);
  const float var = sq * (1.0f / 1024.0f) - mean * mean;
  const float rs = rsqrtf(var + 1e-5f);
  const float4 g4 = ((const float4*)gamma)[t];
  const float4 b4 = ((const float4*)beta)[t];
  ushort4 o4;
  o4.x = f2bf((v.x - mean) * rs * g4.x + b4.x);
  o4.y = f2bf((v.y - mean) * rs * g4.y + b4.y);
  o4.z = f2bf((v.z - mean) * rs * g4.z + b4.z);
  o4.w = f2bf((v.w - mean) * rs * g4.w + b4.w);
  ((ushort4*)(xn + (size_t)row * 1024))[t] = o4;
}

// ---- Weight convert fp32 -> bf16 concat [3072][1024]; Wq scaled by QSCALE ----
__global__ __launch_bounds__(256) void wconv_kernel(
    const float* __restrict__ Wq, const float* __restrict__ Wk,
    const float* __restrict__ Wv, unsigned short* __restrict__ Wcat) {
  const int idx = blockIdx.x * 256 + threadIdx.x;  // 786432 threads x 4 elems
  const int which = idx >> 18;
  const int off = (idx & 262143) << 2;
  const float* src = which == 0 ? Wq : (which == 1 ? Wk : Wv);
  const float sc = which == 0 ? QSCALE : 1.0f;
  float4 v = *(const float4*)(src + off);
  ushort4 o;
  o.x = f2bf(v.x * sc); o.y = f2bf(v.y * sc);
  o.z = f2bf(v.z * sc); o.w = f2bf(v.w * sc);
  *(ushort4*)(Wcat + ((size_t)which << 20) + off) = o;
}

// -------- QKV GEMM: C[8192,3072] = xn @ Wcat^T, scatter to [B,H,S,64] --------
// 256x128 tile, 8 waves (4Mx2N, 64x64 each), mfma32, BK=32.
// Fragment-order LDS: A slot s (s=0..1023) holds elem for frag F=s>>6 (F=mb*2+ks,
// mb=m-block of 32 rows, ks=k-slice of 16), lane s&63: A[mb*32+(l&31)][ks*16+(l>>5)*8].
// B identical with nb (4 n-blocks). Reads are base+lane*16B (conflict-free).
// 3 buffers, counted vmcnt(3), 1 raw barrier per K-step (attn-proven safety).
__global__ __launch_bounds__(512, 4) void qkv_gemm(
    const unsigned short* __restrict__ xn, const unsigned short* __restrict__ Wcat,
    const float* __restrict__ bq, const float* __restrict__ bk,
    const float* __restrict__ bv, unsigned short* __restrict__ Q,
    unsigned short* __restrict__ K, unsigned short* __restrict__ V) {
  __shared__ __align__(16) unsigned short Ash[3][8192];  // 256x32 per buffer
  __shared__ __align__(16) unsigned short Bsh[3][4096];  // 128x32 per buffer
  const int m0 = blockIdx.x * 256;
  const int n0 = blockIdx.y * 128;
  const int t = threadIdx.x;
  const int lane = t & 63, w = t >> 6;
  const int l31 = lane & 31, hi = lane >> 5;
  const int wr = w >> 1, wc = w & 1;
  // Staging source offsets (elements). Thread t covers A slots {t, 512+t}, B slot t.
  // Slot t: F=w -> mb=w>>1(=wr), ks=w&1; offset formula identical for A and B.
  const int off0 = ((w >> 1) * 32 + l31) * 1024 + (w & 1) * 16 + hi * 8;
  const unsigned short* Asrc = xn + (size_t)m0 * 1024 + off0;    // + 131072 for slots 512+t
  const unsigned short* Bsrc = Wcat + (size_t)n0 * 1024 + off0;

#define GSTAGE(ktv, bb)                                          \
  {                                                              \
    gload16(Asrc + (ktv) * 32, &Ash[bb][w * 512]);               \
    gload16(Asrc + 131072 + (ktv) * 32, &Ash[bb][4096 + w * 512]); \
    gload16(Bsrc + (ktv) * 32, &Bsh[bb][w * 512]);               \
  }

  f32x16 acc[2][2] = {};
  GSTAGE(0, 0);
  GSTAGE(1, 1);
  int bufc = 0;
  for (int kt = 0; kt < 32; ++kt) {
    if (kt == 31) {
      asm volatile("s_waitcnt vmcnt(0)" ::: "memory");
    } else {
      asm volatile("s_waitcnt vmcnt(3)" ::: "memory");  // tile kt landed; kt+1 in flight
    }
    __builtin_amdgcn_s_barrier();
    __builtin_amdgcn_s_setprio(1);
#pragma unroll
    for (int ks = 0; ks < 2; ++ks) {
      bf16x8 a0 = *(const bf16x8*)&Ash[bufc][((wr * 4 + ks) * 64 + lane) * 8];
      bf16x8 a1 = *(const bf16x8*)&Ash[bufc][((wr * 4 + 2 + ks) * 64 + lane) * 8];
      bf16x8 b0 = *(const bf16x8*)&Bsh[bufc][((wc * 4 + ks) * 64 + lane) * 8];
      bf16x8 b1 = *(const bf16x8*)&Bsh[bufc][((wc * 4 + 2 + ks) * 64 + lane) * 8];
      acc[0][0] = mfma32(a0, b0, acc[0][0]);
      acc[0][1] = mfma32(a0, b1, acc[0][1]);
      acc[1][0] = mfma32(a1, b0, acc[1][0]);
      acc[1][1] = mfma32(a1, b1, acc[1][1]);
    }
    __builtin_amdgcn_s_setprio(0);
    if (kt + 2 < 32) {
      int nb = bufc + 2; if (nb >= 3) nb -= 3;
      GSTAGE(kt + 2, nb);
    }
    bufc = (bufc + 1 == 3) ? 0 : bufc + 1;
  }
#undef GSTAGE
  const int nsel = n0 >> 10;
  const float* bias = nsel == 0 ? bq : (nsel == 1 ? bk : bv);
  unsigned short* dst = nsel == 0 ? Q : (nsel == 1 ? K : V);
  const float bscale = nsel == 0 ? QSCALE : 1.0f;
  // D layout (32x32): col = l31, row = (r&3) + 8*(r>>2) + 4*hi
#pragma unroll
  for (int ml = 0; ml < 2; ++ml) {
#pragma unroll
    for (int nl = 0; nl < 2; ++nl) {
      const int nc = (n0 & 1023) + wc * 64 + nl * 32 + l31;
      const float bb = bias[nc] * bscale;
      const int h = nc >> 6, dk = nc & 63;
#pragma unroll
      for (int r = 0; r < 16; ++r) {
        const int m = m0 + wr * 64 + ml * 32 + (r & 3) + 8 * (r >> 2) + 4 * hi;
        const int b = m >> 11, sI = m & 2047;
        dst[((size_t)((b * 16 + h) * 2048 + sI)) * 64 + dk] = f2bf(acc[ml][nl][r] + bb);
      }
    }
  }
}

// ------------- V [bh][s][64] -> Vt [bh][64][s] (64x64 LDS tiles) -------------
__global__ __launch_bounds__(256) void vt_kernel(
    const unsigned short* __restrict__ V, unsigned short* __restrict__ Vt) {
  __shared__ unsigned short tile[64][65];
  const int st = blockIdx.x, bh = blockIdx.y;
  const int t = threadIdx.x;
  const unsigned short* Vb = V + ((size_t)bh * 2048 + st * 64) * 64;
#pragma unroll
  for (int i = 0; i < 2; ++i) {
    const int li = i * 256 + t;
    const int s = li >> 3, c = li & 7;
    ushort4 a = *(const ushort4*)(Vb + s * 64 + c * 8);
    ushort4 b = *(const ushort4*)(Vb + s * 64 + c * 8 + 4);
    tile[s][c * 8 + 0] = a.x; tile[s][c * 8 + 1] = a.y;
    tile[s][c * 8 + 2] = a.z; tile[s][c * 8 + 3] = a.w;
    tile[s][c * 8 + 4] = b.x; tile[s][c * 8 + 5] = b.y;
    tile[s][c * 8 + 6] = b.z; tile[s][c * 8 + 7] = b.w;
  }
  __syncthreads();
  unsigned short* dst = Vt + (size_t)bh * 64 * 2048 + st * 64;
#pragma unroll
  for (int i = 0; i < 2; ++i) {
    const int li = i * 256 + t;
    const int d = li >> 3, c = li & 7;
    ushort4 o1, o2;
    o1.x = tile[c * 8 + 0][d]; o1.y = tile[c * 8 + 1][d];
    o1.z = tile[c * 8 + 2][d]; o1.w = tile[c * 8 + 3][d];
    o2.x = tile[c * 8 + 4][d]; o2.y = tile[c * 8 + 5][d];
    o2.z = tile[c * 8 + 6][d]; o2.w = tile[c * 8 + 7][d];
    *(ushort4*)(dst + (size_t)d * 2048 + c * 8) = o1;
    *(ushort4*)(dst + (size_t)d * 2048 + c * 8 + 4) = o2;
  }
}

// ---- flash attention: block = (qt,bh), 256 q-rows, 8 waves x 32 q, 32 KV tiles ----
// Grid 512 blocks 1D; bh%8 == blockIdx.x%8 pins each bh's 8 qt-blocks to one XCD.
// K/V LDS in FRAGMENT ORDER -> ds_read addresses are base + lane*16B (conflict-free).
// 3-buffer staging, counted vmcnt(2), 1 raw barrier/tile.
__global__ __launch_bounds__(512) void attn_kernel(
    const unsigned short* __restrict__ Q, const unsigned short* __restrict__ K,
    const unsigned short* __restrict__ Vt, float* __restrict__ out) {
  __shared__ __align__(16) unsigned short Ksh[3][64 * 64];
  __shared__ __align__(16) unsigned short Vsh[3][64 * 64];
  const int id = blockIdx.x;
  const int k7 = id >> 3;
  const int qt = k7 & 7, bh = (id & 7) + 8 * (k7 >> 3);
  const int t = threadIdx.x, lane = t & 63, w = t >> 6;
  const int l31 = lane & 31, hi = lane >> 5;
  const int b = bh >> 4, h = bh & 15;
  const unsigned short* Qb = Q + (size_t)bh * 2048 * 64;
  const unsigned short* Kb = K + (size_t)bh * 2048 * 64;
  const unsigned short* Vb = Vt + (size_t)bh * 64 * 2048;
  const int q0w = qt * 256 + w * 32;
  // Q as B-operand frags (reg-resident): lane holds Q[q0w+l31][8*hi+j+16*ds]
  bf16x8 qf[4];
#pragma unroll
  for (int ds = 0; ds < 4; ++ds)
    qf[ds] = *(const bf16x8*)(Qb + (size_t)(q0w + l31) * 64 + ds * 16 + hi * 8);
  bf16x8 ones;
#pragma unroll
  for (int j = 0; j < 8; ++j) ones[j] = (__bf16)1.0f;
  f32x16 oacc[2] = {};
  f32x16 lacc = {};

  // Fragment-order staging sources (per-thread constants)
  const int sl31 = t & 31, shi = (t >> 5) & 1;
  const int skb = t >> 8, sds = (t >> 6) & 3;
  const int sks = t >> 7, sdb = (t >> 6) & 1;
  const unsigned short* Ksrc = Kb + (size_t)(skb * 32 + sl31) * 64 + (sds * 2 + shi) * 8;
  const unsigned short* Vsrc = Vb + (size_t)(sdb * 32 + sl31) * 2048 + (sks * 2 + shi) * 8;

#define STAGE(kvt, bb)                                       \
  {                                                          \
    gload16(Ksrc + (size_t)(kvt) * 4096, &Ksh[bb][w * 512]); \
    gload16(Vsrc + (size_t)(kvt) * 64, &Vsh[bb][w * 512]);   \
  }

  STAGE(0, 0);
  STAGE(1, 1);
  int bufc = 0;  // buffer holding tile kv
  for (int kv = 0; kv < 32; ++kv) {
    if (kv == 31) {
      asm volatile("s_waitcnt vmcnt(0)" ::: "memory");
    } else {
      asm volatile("s_waitcnt vmcnt(2)" ::: "memory");  // own tile-kv loads landed
    }
    __builtin_amdgcn_s_barrier();  // all waves' tile-kv loads landed
    bf16x8 pa[4];
#pragma unroll
    for (int kb = 0; kb < 2; ++kb) {
      f32x16 s = {};
      __builtin_amdgcn_s_setprio(1);
#pragma unroll
      for (int ds = 0; ds < 4; ++ds) {
        bf16x8 ak = *(const bf16x8*)&Ksh[bufc][((kb * 4 + ds) * 64 + lane) * 8];
        s = mfma32(ak, qf[ds], s);
      }
      __builtin_amdgcn_s_setprio(0);
      // P = exp2(S) (S in log2-domain), pack to bf16 pairs, cross-lane assemble.
      unsigned int wd[8];
#pragma unroll
      for (int i = 0; i < 8; ++i)
        wd[i] = cvtpk(__builtin_amdgcn_exp2f(s[2 * i]),
                      __builtin_amdgcn_exp2f(s[2 * i + 1]));
      swap32(wd[0], wd[2]); swap32(wd[1], wd[3]);
      swap32(wd[4], wd[6]); swap32(wd[5], wd[7]);
      const u32x4 fa = {wd[0], wd[1], wd[2], wd[3]};
      const u32x4 fb = {wd[4], wd[5], wd[6], wd[7]};
      pa[kb * 2]     = __builtin_bit_cast(bf16x8, fa);
      pa[kb * 2 + 1] = __builtin_bit_cast(bf16x8, fb);
    }
    // PV + row-sum: A = P (regs), B = Vt / ones
    __builtin_amdgcn_s_setprio(1);
#pragma unroll
    for (int ks = 0; ks < 4; ++ks) {
      lacc = mfma32(pa[ks], ones, lacc);
#pragma unroll
      for (int db = 0; db < 2; ++db) {
        bf16x8 bv8 = *(const bf16x8*)&Vsh[bufc][((ks * 2 + db) * 64 + lane) * 8];
        oacc[db] = mfma32(pa[ks], bv8, oacc[db]);
      }
    }
    __builtin_amdgcn_s_setprio(0);
    // Prefetch tile kv+2 into the buffer being retired (disjoint from kv, kv+1)
    if (kv + 2 < 32) {
      int nb = bufc + 2; if (nb >= 3) nb -= 3;
      STAGE(kv + 2, nb);
    }
    bufc = (bufc + 1 == 3) ? 0 : bufc + 1;
  }
#undef STAGE
  // Epilogue: D layout col=l31 (=d within 32-block), row q = (r&3)+8*(r>>2)+4*hi
#pragma unroll
  for (int r = 0; r < 16; ++r) {
    const float inv = 1.0f / lacc[r];
    const int q = q0w + (r & 3) + 8 * (r >> 2) + 4 * hi;
    const size_t base = ((size_t)(b * 2048 + q)) * 1024 + h * 64;
    out[base + l31] = oacc[0][r] * inv;
    out[base + 32 + l31] = oacc[1][r] * inv;
  }
}

extern "C" void kernel_launch(void* const* d_in, const int* in_sizes, int n_in,
                              void* d_out, int out_size, void* d_ws, size_t ws_size,
                              hipStream_t stream) {
  const float* x   = (const float*)d_in[0];
  const float* Wq  = (const float*)d_in[1];
  const float* bq  = (const float*)d_in[2];
  const float* Wk  = (const float*)d_in[3];
  const float* bk  = (const float*)d_in[4];
  const float* Wv  = (const float*)d_in[5];
  const float* bv  = (const float*)d_in[6];
  const float* gam = (const float*)d_in[7];
  const float* bet = (const float*)d_in[8];

  unsigned short* ws   = (unsigned short*)d_ws;
  unsigned short* xn   = ws;                    // 8192*1024
  unsigned short* Wcat = xn + 8192 * 1024;      // 3072*1024
  unsigned short* Qb   = Wcat + 3072 * 1024;    // 64*2048*64
  unsigned short* Kb   = Qb + 64 * 2048 * 64;
  unsigned short* Vb   = Kb + 64 * 2048 * 64;
  unsigned short* Vtb  = Vb + 64 * 2048 * 64;
  float* outp = (float*)d_out;  // fp32 output (reference returns float32)

  hipLaunchKernelGGL(ln_kernel, dim3(8192), dim3(256), 0, stream, x, gam, bet, xn);
  hipLaunchKernelGGL(wconv_kernel, dim3(3072), dim3(256), 0, stream, Wq, Wk, Wv, Wcat);
  hipLaunchKernelGGL(qkv_gemm, dim3(32, 24), dim3(512), 0, stream,
                     xn, Wcat, bq, bk, bv, Qb, Kb, Vb);
  hipLaunchKernelGGL(vt_kernel, dim3(32, 64), dim3(256), 0, stream, Vb, Vtb);
  hipLaunchKernelGGL(attn_kernel, dim3(512), dim3(512), 0, stream, Qb, Kb, Vtb, outp);
}

// Round 13
// 154.902 us; speedup vs baseline: 1.2635x; 1.1006x over previous
//
#include <hip/hip_runtime.h>
#include <cstdint>
#include <cstddef>

// Fused MHA forward: LN -> QKV proj (bf16 MFMA) -> flash attention -> fp32 out.
// R13: qkv_gemm staging made COALESCED while keeping conflict-free reads:
// row-major LDS tiles with within-row chunk XOR (c ^= (row>>1)&3). The XOR stays
// inside each 64B row -> staging lanes still cover contiguous 64B segments
// (16 segments/instr vs 64 scattered 16B requests of R12's fragment-order),
// and wave reads spread uniformly 8-lanes-per-16B-group (optimal).
// Sync structure (3-buf, vmcnt(3), 1 barrier) and all other kernels == R12.
// Workspace layout (ushorts): xn[8192*1024] | Wcat[3072*1024] | Q,K,V,Vt[64*2048*64 each]

typedef __attribute__((ext_vector_type(8))) __bf16 bf16x8;
typedef __attribute__((ext_vector_type(4))) float f32x4;
typedef __attribute__((ext_vector_type(16))) float f32x16;
typedef __attribute__((ext_vector_type(4))) unsigned int u32x4;

#define LOG2E 1.4426950408889634f
#define QSCALE (0.125f * LOG2E)  // 1/sqrt(64) * log2(e), folded into Wq/bq

static __device__ __forceinline__ unsigned short f2bf(float f) {
  union { float f; unsigned int u; } v; v.f = f;
  unsigned int r = v.u + 0x7fffu + ((v.u >> 16) & 1u);
  return (unsigned short)(r >> 16);
}

static __device__ __forceinline__ void gload16(const void* g, void* l) {
  __builtin_amdgcn_global_load_lds(
      (const __attribute__((address_space(1))) unsigned int*)g,
      (__attribute__((address_space(3))) unsigned int*)l, 16, 0, 0);
}

static __device__ __forceinline__ f32x16 mfma32(bf16x8 a, bf16x8 b, f32x16 c) {
  return __builtin_amdgcn_mfma_f32_32x32x16_bf16(a, b, c, 0, 0, 0);
}

static __device__ __forceinline__ unsigned int cvtpk(float lo, float hi) {
  unsigned int r;
  asm("v_cvt_pk_bf16_f32 %0, %1, %2" : "=v"(r) : "v"(lo), "v"(hi));
  return r;
}

// v_permlane32_swap_b32: a'[l<32]=a[l], a'[l>=32]=b[l-32]; b'[l<32]=a[l+32], b'[l>=32]=b[l]
static __device__ __forceinline__ void swap32(unsigned int& a, unsigned int& b) {
  asm("v_permlane32_swap_b32 %0, %1" : "+v"(a), "+v"(b));
}

// ---------------- LayerNorm: x fp32 [8192][1024] -> xn bf16 ----------------
__global__ __launch_bounds__(256) void ln_kernel(
    const float* __restrict__ x, const float* __restrict__ gamma,
    const float* __restrict__ beta, unsigned short* __restrict__ xn) {
  const int row = blockIdx.x;
  const int t = threadIdx.x;
  const float4 v = ((const float4*)(x + (size_t)row * 1024))[t];
  float s = v.x + v.y + v.z + v.w;
  float sq = v.x * v.x + v.y * v.y + v.z * v.z + v.w * v.w;
#pragma unroll
  for (int o = 1; o < 64; o <<= 1) { s += __shfl_xor(s, o); sq += __shfl_xor(sq, o); }
  __shared__ float red[2][4];
  const int lane = t & 63, w = t >> 6;
  if (lane == 0) { red[0][w] = s; red[1][w] = sq; }
  __syncthreads();
  s = red[0][0] + red[0][1] + red[0][2] + red[0][3];
  sq = red[1][0] + red[1][1] + red[1][2] + red[1][3];
  const float mean = s * (1.0f / 1024.0f);
  const float var = sq * (1.0f / 1024.0f) - mean * mean;
  const float rs = rsqrtf(var + 1e-5f);
  const float4 g4 = ((const float4*)gamma)[t];
  const float4 b4 = ((const float4*)beta)[t];
  ushort4 o4;
  o4.x = f2bf((v.x - mean) * rs * g4.x + b4.x);
  o4.y = f2bf((v.y - mean) * rs * g4.y + b4.y);
  o4.z = f2bf((v.z - mean) * rs * g4.z + b4.z);
  o4.w = f2bf((v.w - mean) * rs * g4.w + b4.w);
  ((ushort4*)(xn + (size_t)row * 1024))[t] = o4;
}

// ---- Weight convert fp32 -> bf16 concat [3072][1024]; Wq scaled by QSCALE ----
__global__ __launch_bounds__(256) void wconv_kernel(
    const float* __restrict__ Wq, const float* __restrict__ Wk,
    const float* __restrict__ Wv, unsigned short* __restrict__ Wcat) {
  const int idx = blockIdx.x * 256 + threadIdx.x;  // 786432 threads x 4 elems
  const int which = idx >> 18;
  const int off = (idx & 262143) << 2;
  const float* src = which == 0 ? Wq : (which == 1 ? Wk : Wv);
  const float sc = which == 0 ? QSCALE : 1.0f;
  float4 v = *(const float4*)(src + off);
  ushort4 o;
  o.x = f2bf(v.x * sc); o.y = f2bf(v.y * sc);
  o.z = f2bf(v.z * sc); o.w = f2bf(v.w * sc);
  *(ushort4*)(Wcat + ((size_t)which << 20) + off) = o;
}

// -------- QKV GEMM: C[8192,3072] = xn @ Wcat^T, scatter to [B,H,S,64] --------
// 256x128 tile, 8 waves (4Mx2N, 64x64 each), mfma32, BK=32, 3 buffers,
// counted vmcnt(3), 1 raw barrier per K-step.
// LDS: row-major [rows][32 elems] with 16B-chunk XOR c^=(row>>1)&3 within each
// 64B row. Staging: thread t covers slot (row=t>>2, c=t&3) -> global chunk
// c^((row>>1)&3); 4 consecutive threads = one 64B segment (coalesced).
// Reads: row = (wavequad)*64 + l31 (+32), chunk = (ks*2+hi) ^ ((l31>>1)&3) ->
// uniform 8-lanes-per-16B-group (conflict-free).
__global__ __launch_bounds__(512, 4) void qkv_gemm(
    const unsigned short* __restrict__ xn, const unsigned short* __restrict__ Wcat,
    const float* __restrict__ bq, const float* __restrict__ bk,
    const float* __restrict__ bv, unsigned short* __restrict__ Q,
    unsigned short* __restrict__ K, unsigned short* __restrict__ V) {
  __shared__ __align__(16) unsigned short Ash[3][8192];  // 256x32 per buffer
  __shared__ __align__(16) unsigned short Bsh[3][4096];  // 128x32 per buffer
  const int m0 = blockIdx.x * 256;
  const int n0 = blockIdx.y * 128;
  const int t = threadIdx.x;
  const int lane = t & 63, w = t >> 6;
  const int l31 = lane & 31, hi = lane >> 5;
  const int wr = w >> 1, wc = w & 1;
  const int swz = (l31 >> 1) & 3;  // read-side chunk XOR (row>>1)&3 with row=..+l31
  // Staging source: slot s=i*512+t -> row=s>>2, c=s&3; rows 128 apart share the
  // same (row>>1)&3 (128/2 % 4 == 0), so one offset serves both A halves.
  const int srow = t >> 2, sc = t & 3;
  const int scc = sc ^ ((srow >> 1) & 3);
  const int off0 = srow * 1024 + scc * 8;
  const unsigned short* Asrc = xn + (size_t)m0 * 1024 + off0;    // +131072 for rows 128..255
  const unsigned short* Bsrc = Wcat + (size_t)n0 * 1024 + off0;

#define GSTAGE(ktv, bb)                                            \
  {                                                                \
    gload16(Asrc + (ktv) * 32, &Ash[bb][w * 512]);                 \
    gload16(Asrc + 131072 + (ktv) * 32, &Ash[bb][4096 + w * 512]); \
    gload16(Bsrc + (ktv) * 32, &Bsh[bb][w * 512]);                 \
  }

  f32x16 acc[2][2] = {};
  GSTAGE(0, 0);
  GSTAGE(1, 1);
  const int ra = wr * 64 + l31;  // A row (ml=0); ml=1 adds 32
  const int rb = wc * 64 + l31;  // B row (nl=0); nl=1 adds 32
  int bufc = 0;
  for (int kt = 0; kt < 32; ++kt) {
    if (kt == 31) {
      asm volatile("s_waitcnt vmcnt(0)" ::: "memory");
    } else {
      asm volatile("s_waitcnt vmcnt(3)" ::: "memory");  // tile kt landed; kt+1 in flight
    }
    __builtin_amdgcn_s_barrier();
    __builtin_amdgcn_s_setprio(1);
#pragma unroll
    for (int ks = 0; ks < 2; ++ks) {
      const int ch = ((ks * 2 + hi) ^ swz) * 8;
      bf16x8 a0 = *(const bf16x8*)&Ash[bufc][ra * 32 + ch];
      bf16x8 a1 = *(const bf16x8*)&Ash[bufc][ra * 32 + 1024 + ch];
      bf16x8 b0 = *(const bf16x8*)&Bsh[bufc][rb * 32 + ch];
      bf16x8 b1 = *(const bf16x8*)&Bsh[bufc][rb * 32 + 1024 + ch];
      acc[0][0] = mfma32(a0, b0, acc[0][0]);
      acc[0][1] = mfma32(a0, b1, acc[0][1]);
      acc[1][0] = mfma32(a1, b0, acc[1][0]);
      acc[1][1] = mfma32(a1, b1, acc[1][1]);
    }
    __builtin_amdgcn_s_setprio(0);
    if (kt + 2 < 32) {
      int nb = bufc + 2; if (nb >= 3) nb -= 3;
      GSTAGE(kt + 2, nb);
    }
    bufc = (bufc + 1 == 3) ? 0 : bufc + 1;
  }
#undef GSTAGE
  const int nsel = n0 >> 10;
  const float* bias = nsel == 0 ? bq : (nsel == 1 ? bk : bv);
  unsigned short* dst = nsel == 0 ? Q : (nsel == 1 ? K : V);
  const float bscale = nsel == 0 ? QSCALE : 1.0f;
  // D layout (32x32): col = l31, row = (r&3) + 8*(r>>2) + 4*hi
#pragma unroll
  for (int ml = 0; ml < 2; ++ml) {
#pragma unroll
    for (int nl = 0; nl < 2; ++nl) {
      const int nc = (n0 & 1023) + wc * 64 + nl * 32 + l31;
      const float bb = bias[nc] * bscale;
      const int h = nc >> 6, dk = nc & 63;
#pragma unroll
      for (int r = 0; r < 16; ++r) {
        const int m = m0 + wr * 64 + ml * 32 + (r & 3) + 8 * (r >> 2) + 4 * hi;
        const int b = m >> 11, sI = m & 2047;
        dst[((size_t)((b * 16 + h) * 2048 + sI)) * 64 + dk] = f2bf(acc[ml][nl][r] + bb);
      }
    }
  }
}

// ------------- V [bh][s][64] -> Vt [bh][64][s] (64x64 LDS tiles) -------------
__global__ __launch_bounds__(256) void vt_kernel(
    const unsigned short* __restrict__ V, unsigned short* __restrict__ Vt) {
  __shared__ unsigned short tile[64][65];
  const int st = blockIdx.x, bh = blockIdx.y;
  const int t = threadIdx.x;
  const unsigned short* Vb = V + ((size_t)bh * 2048 + st * 64) * 64;
#pragma unroll
  for (int i = 0; i < 2; ++i) {
    const int li = i * 256 + t;
    const int s = li >> 3, c = li & 7;
    ushort4 a = *(const ushort4*)(Vb + s * 64 + c * 8);
    ushort4 b = *(const ushort4*)(Vb + s * 64 + c * 8 + 4);
    tile[s][c * 8 + 0] = a.x; tile[s][c * 8 + 1] = a.y;
    tile[s][c * 8 + 2] = a.z; tile[s][c * 8 + 3] = a.w;
    tile[s][c * 8 + 4] = b.x; tile[s][c * 8 + 5] = b.y;
    tile[s][c * 8 + 6] = b.z; tile[s][c * 8 + 7] = b.w;
  }
  __syncthreads();
  unsigned short* dst = Vt + (size_t)bh * 64 * 2048 + st * 64;
#pragma unroll
  for (int i = 0; i < 2; ++i) {
    const int li = i * 256 + t;
    const int d = li >> 3, c = li & 7;
    ushort4 o1, o2;
    o1.x = tile[c * 8 + 0][d]; o1.y = tile[c * 8 + 1][d];
    o1.z = tile[c * 8 + 2][d]; o1.w = tile[c * 8 + 3][d];
    o2.x = tile[c * 8 + 4][d]; o2.y = tile[c * 8 + 5][d];
    o2.z = tile[c * 8 + 6][d]; o2.w = tile[c * 8 + 7][d];
    *(ushort4*)(dst + (size_t)d * 2048 + c * 8) = o1;
    *(ushort4*)(dst + (size_t)d * 2048 + c * 8 + 4) = o2;
  }
}

// ---- flash attention: block = (qt,bh), 256 q-rows, 8 waves x 32 q, 32 KV tiles ----
// Grid 512 blocks 1D; bh%8 == blockIdx.x%8 pins each bh's 8 qt-blocks to one XCD.
// K/V LDS in FRAGMENT ORDER -> ds_read addresses are base + lane*16B (conflict-free).
// 3-buffer staging, counted vmcnt(2), 1 raw barrier/tile.
__global__ __launch_bounds__(512) void attn_kernel(
    const unsigned short* __restrict__ Q, const unsigned short* __restrict__ K,
    const unsigned short* __restrict__ Vt, float* __restrict__ out) {
  __shared__ __align__(16) unsigned short Ksh[3][64 * 64];
  __shared__ __align__(16) unsigned short Vsh[3][64 * 64];
  const int id = blockIdx.x;
  const int k7 = id >> 3;
  const int qt = k7 & 7, bh = (id & 7) + 8 * (k7 >> 3);
  const int t = threadIdx.x, lane = t & 63, w = t >> 6;
  const int l31 = lane & 31, hi = lane >> 5;
  const int b = bh >> 4, h = bh & 15;
  const unsigned short* Qb = Q + (size_t)bh * 2048 * 64;
  const unsigned short* Kb = K + (size_t)bh * 2048 * 64;
  const unsigned short* Vb = Vt + (size_t)bh * 64 * 2048;
  const int q0w = qt * 256 + w * 32;
  // Q as B-operand frags (reg-resident): lane holds Q[q0w+l31][8*hi+j+16*ds]
  bf16x8 qf[4];
#pragma unroll
  for (int ds = 0; ds < 4; ++ds)
    qf[ds] = *(const bf16x8*)(Qb + (size_t)(q0w + l31) * 64 + ds * 16 + hi * 8);
  bf16x8 ones;
#pragma unroll
  for (int j = 0; j < 8; ++j) ones[j] = (__bf16)1.0f;
  f32x16 oacc[2] = {};
  f32x16 lacc = {};

  // Fragment-order staging sources (per-thread constants)
  const int sl31 = t & 31, shi = (t >> 5) & 1;
  const int skb = t >> 8, sds = (t >> 6) & 3;
  const int sks = t >> 7, sdb = (t >> 6) & 1;
  const unsigned short* Ksrc = Kb + (size_t)(skb * 32 + sl31) * 64 + (sds * 2 + shi) * 8;
  const unsigned short* Vsrc = Vb + (size_t)(sdb * 32 + sl31) * 2048 + (sks * 2 + shi) * 8;

#define STAGE(kvt, bb)                                       \
  {                                                          \
    gload16(Ksrc + (size_t)(kvt) * 4096, &Ksh[bb][w * 512]); \
    gload16(Vsrc + (size_t)(kvt) * 64, &Vsh[bb][w * 512]);   \
  }

  STAGE(0, 0);
  STAGE(1, 1);
  int bufc = 0;  // buffer holding tile kv
  for (int kv = 0; kv < 32; ++kv) {
    if (kv == 31) {
      asm volatile("s_waitcnt vmcnt(0)" ::: "memory");
    } else {
      asm volatile("s_waitcnt vmcnt(2)" ::: "memory");  // own tile-kv loads landed
    }
    __builtin_amdgcn_s_barrier();  // all waves' tile-kv loads landed
    bf16x8 pa[4];
#pragma unroll
    for (int kb = 0; kb < 2; ++kb) {
      f32x16 s = {};
      __builtin_amdgcn_s_setprio(1);
#pragma unroll
      for (int ds = 0; ds < 4; ++ds) {
        bf16x8 ak = *(const bf16x8*)&Ksh[bufc][((kb * 4 + ds) * 64 + lane) * 8];
        s = mfma32(ak, qf[ds], s);
      }
      __builtin_amdgcn_s_setprio(0);
      // P = exp2(S) (S in log2-domain), pack to bf16 pairs, cross-lane assemble.
      unsigned int wd[8];
#pragma unroll
      for (int i = 0; i < 8; ++i)
        wd[i] = cvtpk(__builtin_amdgcn_exp2f(s[2 * i]),
                      __builtin_amdgcn_exp2f(s[2 * i + 1]));
      swap32(wd[0], wd[2]); swap32(wd[1], wd[3]);
      swap32(wd[4], wd[6]); swap32(wd[5], wd[7]);
      const u32x4 fa = {wd[0], wd[1], wd[2], wd[3]};
      const u32x4 fb = {wd[4], wd[5], wd[6], wd[7]};
      pa[kb * 2]     = __builtin_bit_cast(bf16x8, fa);
      pa[kb * 2 + 1] = __builtin_bit_cast(bf16x8, fb);
    }
    // PV + row-sum: A = P (regs), B = Vt / ones
    __builtin_amdgcn_s_setprio(1);
#pragma unroll
    for (int ks = 0; ks < 4; ++ks) {
      lacc = mfma32(pa[ks], ones, lacc);
#pragma unroll
      for (int db = 0; db < 2; ++db) {
        bf16x8 bv8 = *(const bf16x8*)&Vsh[bufc][((ks * 2 + db) * 64 + lane) * 8];
        oacc[db] = mfma32(pa[ks], bv8, oacc[db]);
      }
    }
    __builtin_amdgcn_s_setprio(0);
    // Prefetch tile kv+2 into the buffer being retired (disjoint from kv, kv+1)
    if (kv + 2 < 32) {
      int nb = bufc + 2; if (nb >= 3) nb -= 3;
      STAGE(kv + 2, nb);
    }
    bufc = (bufc + 1 == 3) ? 0 : bufc + 1;
  }
#undef STAGE
  // Epilogue: D layout col=l31 (=d within 32-block), row q = (r&3)+8*(r>>2)+4*hi
#pragma unroll
  for (int r = 0; r < 16; ++r) {
    const float inv = 1.0f / lacc[r];
    const int q = q0w + (r & 3) + 8 * (r >> 2) + 4 * hi;
    const size_t base = ((size_t)(b * 2048 + q)) * 1024 + h * 64;
    out[base + l31] = oacc[0][r] * inv;
    out[base + 32 + l31] = oacc[1][r] * inv;
  }
}

extern "C" void kernel_launch(void* const* d_in, const int* in_sizes, int n_in,
                              void* d_out, int out_size, void* d_ws, size_t ws_size,
                              hipStream_t stream) {
  const float* x   = (const float*)d_in[0];
  const float* Wq  = (const float*)d_in[1];
  const float* bq  = (const float*)d_in[2];
  const float* Wk  = (const float*)d_in[3];
  const float* bk  = (const float*)d_in[4];
  const float* Wv  = (const float*)d_in[5];
  const float* bv  = (const float*)d_in[6];
  const float* gam = (const float*)d_in[7];
  const float* bet = (const float*)d_in[8];

  unsigned short* ws   = (unsigned short*)d_ws;
  unsigned short* xn   = ws;                    // 8192*1024
  unsigned short* Wcat = xn + 8192 * 1024;      // 3072*1024
  unsigned short* Qb   = Wcat + 3072 * 1024;    // 64*2048*64
  unsigned short* Kb   = Qb + 64 * 2048 * 64;
  unsigned short* Vb   = Kb + 64 * 2048 * 64;
  unsigned short* Vtb  = Vb + 64 * 2048 * 64;
  float* outp = (float*)d_out;  // fp32 output (reference returns float32)

  hipLaunchKernelGGL(ln_kernel, dim3(8192), dim3(256), 0, stream, x, gam, bet, xn);
  hipLaunchKernelGGL(wconv_kernel, dim3(3072), dim3(256), 0, stream, Wq, Wk, Wv, Wcat);
  hipLaunchKernelGGL(qkv_gemm, dim3(32, 24), dim3(512), 0, stream,
                     xn, Wcat, bq, bk, bv, Qb, Kb, Vb);
  hipLaunchKernelGGL(vt_kernel, dim3(32, 64), dim3(256), 0, stream, Vb, Vtb);
  hipLaunchKernelGGL(attn_kernel, dim3(512), dim3(512), 0, stream, Qb, Kb, Vtb, outp);
}